// Round 4
// baseline (21258.723 us; speedup 1.0000x reference)
//
#include <hip/hip_runtime.h>
#include <math.h>

#define NB 128
#define NS 256
#define ND 512
#define NBS (NB*NS)   // 32768

// ---------------- device-global scratch (all f64) ----------------
__device__ double g_x[(size_t)NBS * ND];       // [B][S][512] embedded+summed
__device__ double g_P1[(size_t)NBS * ND];      // [B][S][512] leap input-side preact (xt,b1,bc parts)
__device__ double g_Pcell[(size_t)NBS * 2048]; // [B][S][2048] xt @ cell_Wih^T
__device__ double g_Aproj[(size_t)NBS * 40];   // x @ rev_Wih^T
__device__ double g_bc[(size_t)NBS * 32];      // cols 0..9 back, 10..29 cnn
__device__ double g_gum[NS * NB * 2];          // log(-log(u+EPS)+EPS), layout (S,B,2)
__device__ double g_hx[NB * ND];
__device__ double g_c[NB * ND];
__device__ double g_gbuf[NB * 2560];           // per-step: 0..2047 cell gates, 2048..2559 leap pre-hidden
__device__ double g_final[NB * ND];

__device__ __forceinline__ double sigd(double x) { return 1.0 / (1.0 + exp(-x)); }

// ---------------- init ----------------
__global__ void init_state() {
    int i = blockIdx.x * 256 + threadIdx.x;
    if (i < NB * ND) { g_hx[i] = 0.0; g_c[i] = 0.0; }
}

// ---------------- gumbel: JAX PARTITIONABLE threefry2x32, key (0,42) ----------------
// Modern JAX (jax_threefry_partitionable=True, default since ~0.4.36):
//   counts = iota(uint64, size); hi = counts>>32 (==0 here), lo = counts&0xffffffff
//   (o0,o1) = threefry2x32(key=(0,42), ctr=(hi,lo));  bits = o0 ^ o1
//   u = bitcast((bits>>9)|0x3f800000) - 1;  direct reshape to (S,B,2)
__device__ __forceinline__ unsigned rotl32(unsigned x, int r) { return (x << r) | (x >> (32 - r)); }

__global__ void gumbel_init() {
    unsigned p = blockIdx.x * 256 + threadIdx.x;   // element index 0..65535
    if (p >= 65536u) return;
    unsigned k0 = 0u, k1 = 42u;
    unsigned ks2 = k0 ^ k1 ^ 0x1BD11BDAu;
    unsigned x0 = 0u;          // hi word of 64-bit counter (always 0 for size<2^32)
    unsigned x1 = p;           // lo word
    x0 += k0; x1 += k1;
#define RND(r) { x0 += x1; x1 = rotl32(x1, (r)); x1 ^= x0; }
    RND(13) RND(15) RND(26) RND(6)
    x0 += k1;  x1 += ks2 + 1u;
    RND(17) RND(29) RND(16) RND(24)
    x0 += ks2; x1 += k0 + 2u;
    RND(13) RND(15) RND(26) RND(6)
    x0 += k0;  x1 += k1 + 3u;
    RND(17) RND(29) RND(16) RND(24)
    x0 += k1;  x1 += ks2 + 4u;
    RND(13) RND(15) RND(26) RND(6)
    x0 += ks2; x1 += k0 + 5u;
#undef RND
    unsigned bits = x0 ^ x1;
    float u = __uint_as_float((bits >> 9) | 0x3f800000u) - 1.0f;  // exact f32 uniform
    g_gum[p] = log(-log((double)u + 1e-20) + 1e-20);
}

// ---------------- embedding gather+sum (f64 accumulate) ----------------
__global__ __launch_bounds__(128) void embed_sum(const int* __restrict__ seqs,
                                                 const float* __restrict__ emb) {
    int bs = blockIdx.x;            // b*NS + s
    int tid = threadIdx.x;          // 128 threads x 4 elems = 512
    __shared__ int idxs[16];
    if (tid < 16) idxs[tid] = seqs[(size_t)bs * 16 + tid];
    __syncthreads();
    double a0 = 0, a1 = 0, a2 = 0, a3 = 0;
    for (int v = 0; v < 16; ++v) {
        const float4* row = (const float4*)(emb + (size_t)idxs[v] * ND);
        float4 e = row[tid];
        a0 += (double)e.x; a1 += (double)e.y; a2 += (double)e.z; a3 += (double)e.w;
    }
    double* o = g_x + (size_t)bs * ND + tid * 4;
    o[0] = a0; o[1] = a1; o[2] = a2; o[3] = a3;
}

// ---------------- generic f64 GEMM: C[M,N] = (accum?C:0) + bias + A[M,K] @ W[N,K]^T ----------------
__global__ __launch_bounds__(256) void gemm_f64(
    const double* __restrict__ A, int lda,
    const float* __restrict__ W, int ldw,
    double* __restrict__ C, int ldc,
    int M, int N, int K,
    const float* __restrict__ bias, int accum) {
    __shared__ double As[16][66];
    __shared__ double Ws[16][66];
    int m0 = blockIdx.x * 64, n0 = blockIdx.y * 64;
    int tid = threadIdx.x, tx = tid & 15, ty = tid >> 4;
    double acc[4][4] = {};
    for (int k0 = 0; k0 < K; k0 += 16) {
        for (int i = tid; i < 1024; i += 256) {
            int r = i >> 4, c = i & 15;
            As[c][r] = (m0 + r < M && k0 + c < K) ? A[(size_t)(m0 + r) * lda + k0 + c] : 0.0;
            Ws[c][r] = (n0 + r < N && k0 + c < K) ? (double)W[(size_t)(n0 + r) * ldw + k0 + c] : 0.0;
        }
        __syncthreads();
#pragma unroll
        for (int kk = 0; kk < 16; ++kk) {
            double a0 = As[kk][ty*4], a1 = As[kk][ty*4+1], a2 = As[kk][ty*4+2], a3 = As[kk][ty*4+3];
            double w0 = Ws[kk][tx*4], w1 = Ws[kk][tx*4+1], w2 = Ws[kk][tx*4+2], w3 = Ws[kk][tx*4+3];
            acc[0][0] += a0*w0; acc[0][1] += a0*w1; acc[0][2] += a0*w2; acc[0][3] += a0*w3;
            acc[1][0] += a1*w0; acc[1][1] += a1*w1; acc[1][2] += a1*w2; acc[1][3] += a1*w3;
            acc[2][0] += a2*w0; acc[2][1] += a2*w1; acc[2][2] += a2*w2; acc[2][3] += a2*w3;
            acc[3][0] += a3*w0; acc[3][1] += a3*w1; acc[3][2] += a3*w2; acc[3][3] += a3*w3;
        }
        __syncthreads();
    }
#pragma unroll
    for (int i = 0; i < 4; ++i)
#pragma unroll
        for (int j = 0; j < 4; ++j) {
            int m = m0 + ty*4 + i, n = n0 + tx*4 + j;
            if (m < M && n < N) {
                double v = acc[i][j] + (bias ? (double)bias[n] : 0.0);
                if (accum) v += C[(size_t)m * ldc + n];
                C[(size_t)m * ldc + n] = v;
            }
        }
}

// ---------------- reverse LSTM (hidden=10), f64 ----------------
__global__ __launch_bounds__(64) void rev_lstm(const float* __restrict__ Whh /*[40][10]*/) {
    int b = blockIdx.x;
    int tid = threadIdx.x;
    __shared__ double h[10], cc[10], g[40], wsh[400];
    for (int i = tid; i < 400; i += 64) wsh[i] = (double)Whh[i];
    if (tid < 10) { h[tid] = 0.0; cc[tid] = 0.0; }
    __syncthreads();
    for (int s = NS - 1; s >= 0; --s) {
        if (tid < 40) {
            double acc = g_Aproj[((size_t)b * NS + s) * 40 + tid];
#pragma unroll
            for (int k = 0; k < 10; ++k) acc += h[k] * wsh[tid * 10 + k];
            g[tid] = acc;
        }
        __syncthreads();
        if (tid < 10) {
            double gi = g[tid], gf = g[10 + tid], gg = g[20 + tid], go = g[30 + tid];
            double cn = sigd(gf) * cc[tid] + sigd(gi) * tanh(gg);
            cc[tid] = cn;
            double hn = sigd(go) * tanh(cn);
            h[tid] = hn;
            g_bc[((size_t)b * NS + s) * 32 + tid] = hn;   // back cols 0..9
        }
        __syncthreads();
    }
}

// ---------------- conv1d(512->20, k=3, pad=1) + relu, f64; 32-lane group per s-slot ----------------
__global__ __launch_bounds__(256) void conv_relu(const float* __restrict__ w /*[20][512][3]*/) {
    int b = blockIdx.x, s0 = blockIdx.y * 8;
    int tid = threadIdx.x, grp = tid >> 5, lane = tid & 31;
    __shared__ double xs[10][ND];
    for (int i = tid; i < 10 * ND; i += 256) {
        int r = i >> 9, d = i & (ND - 1);
        int s = s0 - 1 + r;
        xs[r][d] = (s >= 0 && s < NS) ? g_x[((size_t)b * NS + s) * ND + d] : 0.0;
    }
    __syncthreads();
    int s = s0 + grp;
    for (int o = 0; o < 20; ++o) {
        const float* wo = w + (size_t)o * 1536;
        double acc = 0.0;
        for (int d = lane; d < ND; d += 32) {
            acc += xs[grp][d]     * (double)wo[d*3]
                 + xs[grp + 1][d] * (double)wo[d*3 + 1]
                 + xs[grp + 2][d] * (double)wo[d*3 + 2];
        }
        for (int m = 16; m > 0; m >>= 1) acc += __shfl_xor(acc, m, 32);
        if (lane == 0)
            g_bc[((size_t)b * NS + s) * 32 + 10 + o] = acc > 0.0 ? acc : 0.0;  // cnn cols 10..29
    }
}

// ---------------- per-step GEMM: g_gbuf[128,2560] = hx @ [cWhh | W1_hx]^T + base ----------------
__global__ __launch_bounds__(256) void step_gemm(
    const float* __restrict__ cWhh, const float* __restrict__ W1, int t) {
    int m0 = blockIdx.x * 32, n0 = blockIdx.y * 64;
    int tid = threadIdx.x, tx = tid & 15, ty = tid >> 4;
    bool leap = (n0 >= 2048);
    const float* Wsrc = leap ? (W1 + (size_t)(n0 - 2048) * 1054) : (cWhh + (size_t)n0 * ND);
    int wld = leap ? 1054 : ND;
    __shared__ double As[32][33];
    __shared__ double Ws[32][66];
    double acc[2][4] = {};
    for (int k0 = 0; k0 < ND; k0 += 32) {
        for (int i = tid; i < 1024; i += 256) {
            int r = i >> 5, c = i & 31;
            As[c][r] = g_hx[(size_t)(m0 + r) * ND + k0 + c];
        }
        for (int i = tid; i < 2048; i += 256) {
            int r = i >> 5, c = i & 31;
            Ws[c][r] = (double)Wsrc[(size_t)r * wld + k0 + c];
        }
        __syncthreads();
#pragma unroll
        for (int kk = 0; kk < 32; ++kk) {
            double a0 = As[kk][ty*2], a1 = As[kk][ty*2+1];
            double w0 = Ws[kk][tx*4], w1 = Ws[kk][tx*4+1], w2 = Ws[kk][tx*4+2], w3 = Ws[kk][tx*4+3];
            acc[0][0] += a0*w0; acc[0][1] += a0*w1; acc[0][2] += a0*w2; acc[0][3] += a0*w3;
            acc[1][0] += a1*w0; acc[1][1] += a1*w1; acc[1][2] += a1*w2; acc[1][3] += a1*w3;
        }
        __syncthreads();
    }
#pragma unroll
    for (int i = 0; i < 2; ++i)
#pragma unroll
        for (int j = 0; j < 4; ++j) {
            int m = m0 + ty*2 + i, n = n0 + tx*4 + j;
            double base = leap ? g_P1[((size_t)m * NS + t) * ND + (n - 2048)]
                               : g_Pcell[((size_t)m * NS + t) * 2048 + n];
            g_gbuf[(size_t)m * 2560 + n] = acc[i][j] + base;
        }
}

// ---------------- per-step elementwise: logits, skip, LSTM cell, gated hx (f64) ----------------
__global__ __launch_bounds__(256) void step_update(
    const float* __restrict__ W2 /*[2][512]*/, const float* __restrict__ b2,
    const int* __restrict__ lengths, int t) {
    int b = blockIdx.x, tid = threadIdx.x;
    const double* gb = g_gbuf + (size_t)b * 2560;
    __shared__ double red[256][2];
    __shared__ double skipsh[2];
    double p0 = 0.0, p1 = 0.0;
    for (int j = tid; j < ND; j += 256) {
        double h = gb[2048 + j];
        h = h > 0.0 ? h : 0.0;              // relu
        p0 += h * (double)W2[j];
        p1 += h * (double)W2[ND + j];
    }
    red[tid][0] = p0; red[tid][1] = p1;
    __syncthreads();
    for (int s = 128; s > 0; s >>= 1) {
        if (tid < s) { red[tid][0] += red[tid + s][0]; red[tid][1] += red[tid + s][1]; }
        __syncthreads();
    }
    if (tid == 0) {
        double l0 = red[0][0] + (double)b2[0], l1 = red[0][1] + (double)b2[1];
        double mx = fmax(l0, l1);
        double sh0 = l0 - mx, sh1 = l1 - mx;
        double lsum = log(exp(sh0) + exp(sh1));
        double y0 = (sh0 - lsum) - g_gum[(size_t)t * (NB * 2) + b * 2 + 0];
        double y1 = (sh1 - lsum) - g_gum[(size_t)t * (NB * 2) + b * 2 + 1];
        double xx0 = y0 / 1e-5, xx1 = y1 / 1e-5;
        double mm = fmax(xx0, xx1);
        double e0 = exp(xx0 - mm), e1 = exp(xx1 - mm);
        double inv = 1.0 / (e0 + e1);
        skipsh[0] = e0 * inv; skipsh[1] = e1 * inv;
    }
    __syncthreads();
    double s0 = skipsh[0], s1 = skipsh[1];
    bool isFinal = (t == lengths[b] - 1);
    for (int j = tid; j < ND; j += 256) {
        double gi = gb[j], gf = gb[ND + j], gg = gb[2*ND + j], go = gb[3*ND + j];
        size_t ix = (size_t)b * ND + j;
        double cn = sigd(gf) * g_c[ix] + sigd(gi) * tanh(gg);
        double shx = sigd(go) * tanh(cn);
        double hn = g_hx[ix] * s1 + shx * s0;
        g_c[ix] = cn;
        g_hx[ix] = hn;
        if (isFinal) g_final[ix] = hn;
    }
}

// ---------------- final projection ----------------
__global__ __launch_bounds__(256) void final_out(const float* __restrict__ Wo,
                                                 const float* __restrict__ bo,
                                                 float* __restrict__ out) {
    int tid = threadIdx.x;             // 256 = 128 b x 2 k
    int b = tid >> 1, k = tid & 1;
    double acc = 0.0;
    const double* f = g_final + (size_t)b * ND;
    const float* w = Wo + (size_t)k * ND;
    for (int d = 0; d < ND; ++d) acc += f[d] * (double)w[d];
    out[b * 2 + k] = (float)(acc + (double)bo[k]);
}

// ---------------- host launcher ----------------
extern "C" void kernel_launch(void* const* d_in, const int* in_sizes, int n_in,
                              void* d_out, int out_size, void* d_ws, size_t ws_size,
                              hipStream_t stream) {
    (void)in_sizes; (void)n_in; (void)d_ws; (void)ws_size; (void)out_size;
    const int*   seqs    = (const int*)d_in[0];
    const int*   lengths = (const int*)d_in[2];
    const float* emb     = (const float*)d_in[5];
    const float* revWih  = (const float*)d_in[6];
    const float* revWhh  = (const float*)d_in[7];
    const float* convw   = (const float*)d_in[8];
    const float* W1      = (const float*)d_in[9];
    const float* b1      = (const float*)d_in[10];
    const float* W2      = (const float*)d_in[11];
    const float* b2      = (const float*)d_in[12];
    const float* cWih    = (const float*)d_in[13];
    const float* cWhh    = (const float*)d_in[14];
    const float* Wo      = (const float*)d_in[15];
    const float* bo      = (const float*)d_in[16];
    float* out = (float*)d_out;

    double *x_p = nullptr, *P1_p = nullptr, *Pc_p = nullptr, *Ap_p = nullptr, *bc_p = nullptr;
    hipGetSymbolAddress((void**)&x_p,  HIP_SYMBOL(g_x));
    hipGetSymbolAddress((void**)&P1_p, HIP_SYMBOL(g_P1));
    hipGetSymbolAddress((void**)&Pc_p, HIP_SYMBOL(g_Pcell));
    hipGetSymbolAddress((void**)&Ap_p, HIP_SYMBOL(g_Aproj));
    hipGetSymbolAddress((void**)&bc_p, HIP_SYMBOL(g_bc));

    init_state<<<256, 256, 0, stream>>>();
    gumbel_init<<<256, 256, 0, stream>>>();
    embed_sum<<<NBS, 128, 0, stream>>>(seqs, emb);

    // Aproj = x @ rev_Wih^T   [32768,512] @ [40,512]^T
    gemm_f64<<<dim3(NBS / 64, 1), 256, 0, stream>>>(x_p, ND, revWih, ND, Ap_p, 40,
                                                    NBS, 40, ND, nullptr, 0);
    rev_lstm<<<NB, 64, 0, stream>>>(revWhh);
    conv_relu<<<dim3(NB, NS / 8), 256, 0, stream>>>(convw);

    // P1 = x @ W1_xt^T + b1   (W1 cols 512..1023)
    gemm_f64<<<dim3(NBS / 64, ND / 64), 256, 0, stream>>>(x_p, ND, W1 + 512, 1054, P1_p, ND,
                                                          NBS, ND, ND, b1, 0);
    // P1 += [back|cnn] @ W1_bc^T (W1 cols 1024..1053, K=30)
    gemm_f64<<<dim3(NBS / 64, ND / 64), 256, 0, stream>>>(bc_p, 32, W1 + 1024, 1054, P1_p, ND,
                                                          NBS, ND, 30, nullptr, 1);
    // Pcell = x @ cell_Wih^T  [32768,512] @ [2048,512]^T
    gemm_f64<<<dim3(NBS / 64, 2048 / 64), 256, 0, stream>>>(x_p, ND, cWih, ND, Pc_p, 2048,
                                                            NBS, 2048, ND, nullptr, 0);

    for (int t = 0; t < NS; ++t) {
        step_gemm<<<dim3(4, 40), 256, 0, stream>>>(cWhh, W1, t);
        step_update<<<NB, 256, 0, stream>>>(W2, b2, lengths, t);
    }
    final_out<<<1, 256, 0, stream>>>(Wo, bo, out);
}